// Round 3
// baseline (324.530 us; speedup 1.0000x reference)
//
#include <hip/hip_runtime.h>

typedef float floatx4 __attribute__((ext_vector_type(4)));
typedef __bf16 bfx8 __attribute__((ext_vector_type(8)));
typedef __bf16 bfx4 __attribute__((ext_vector_type(4)));

// Problem constants
constexpr int B_ = 2, S_ = 2048, H_ = 2048, NH_ = 16, NKV_ = 4, HD_ = 64;
constexpr int M_ = B_ * S_;               // 4096 rows
constexpr int NQKV_ = NH_ * HD_ + 2 * NKV_ * HD_; // 1536
constexpr int HQ_ = NH_ * HD_;            // 1024

// ---------------- kernel: fp32 -> bf16 cast (x4 vectorized) ----------------
__global__ __launch_bounds__(256) void cast_f32_bf16(const float* __restrict__ src,
                                                     __bf16* __restrict__ dst, int n4) {
  int i = blockIdx.x * 256 + threadIdx.x;
  if (i >= n4) return;
  float4 v = ((const float4*)src)[i];
  bfx4 o;
  o[0] = (__bf16)v.x; o[1] = (__bf16)v.y; o[2] = (__bf16)v.z; o[3] = (__bf16)v.w;
  ((bfx4*)dst)[i] = o;
}

// ---------------- kernel: transpose + cast: dst[n+off][k] = src[k][n] ----------------
__global__ __launch_bounds__(256) void transpose_cast(const float* __restrict__ src,
                                                      __bf16* __restrict__ dst,
                                                      int K, int N, int dstOff, int dstPitch) {
  __shared__ float tile[32][33];
  int n0 = blockIdx.x * 32, k0 = blockIdx.y * 32;
  int tx = threadIdx.x, ty = threadIdx.y; // block (32,8)
#pragma unroll
  for (int r = 0; r < 32; r += 8)
    tile[ty + r][tx] = src[(size_t)(k0 + ty + r) * N + n0 + tx];
  __syncthreads();
#pragma unroll
  for (int r = 0; r < 32; r += 8)
    dst[(size_t)(n0 + ty + r + dstOff) * dstPitch + k0 + tx] = (__bf16)tile[tx][ty + r];
}

// ---------------- kernel: bf16 MFMA GEMM. A: MxK row-major, Bt: NxK row-major, C: MxN fp32
__global__ __launch_bounds__(256) void gemm_bf16_f32(const __bf16* __restrict__ A,
                                                     const __bf16* __restrict__ Bt,
                                                     float* __restrict__ C,
                                                     int M, int N, int K) {
  __shared__ __align__(16) __bf16 As[128][72];
  __shared__ __align__(16) __bf16 Bs[128][72];
  int wid = threadIdx.x >> 6, lane = threadIdx.x & 63;
  int l15 = lane & 15, quad = lane >> 4;
  int wm = (wid >> 1) * 64, wn = (wid & 1) * 64;
  int m0 = blockIdx.y * 128, n0 = blockIdx.x * 128;
  floatx4 acc[4][4] = {};
  for (int kb = 0; kb < K; kb += 64) {
#pragma unroll
    for (int i = 0; i < 4; i++) {
      int c = i * 256 + threadIdx.x;
      int r = c >> 3, col = (c & 7) * 8;
      *(bfx8*)&As[r][col] = *(const bfx8*)&A[(size_t)(m0 + r) * K + kb + col];
      *(bfx8*)&Bs[r][col] = *(const bfx8*)&Bt[(size_t)(n0 + r) * K + kb + col];
    }
    __syncthreads();
#pragma unroll
    for (int kk = 0; kk < 64; kk += 32) {
      bfx8 af[4], bfr[4];
#pragma unroll
      for (int mi = 0; mi < 4; mi++)
        af[mi] = *(const bfx8*)&As[wm + mi * 16 + l15][kk + quad * 8];
#pragma unroll
      for (int ni = 0; ni < 4; ni++)
        bfr[ni] = *(const bfx8*)&Bs[wn + ni * 16 + l15][kk + quad * 8];
#pragma unroll
      for (int mi = 0; mi < 4; mi++)
#pragma unroll
        for (int ni = 0; ni < 4; ni++)
          acc[mi][ni] = __builtin_amdgcn_mfma_f32_16x16x32_bf16(af[mi], bfr[ni], acc[mi][ni], 0, 0, 0);
    }
    __syncthreads();
  }
#pragma unroll
  for (int mi = 0; mi < 4; mi++)
#pragma unroll
    for (int ni = 0; ni < 4; ni++) {
      int row = m0 + wm + mi * 16 + quad * 4;
      int coln = n0 + wn + ni * 16 + l15;
#pragma unroll
      for (int r = 0; r < 4; r++)
        C[(size_t)(row + r) * N + coln] = acc[mi][ni][r];
    }
}

// ---------------- kernel: RMSNorm + RoPE on q/k, cast+layout for attention ----------------
__global__ __launch_bounds__(256) void norm_rope_kernel(const float* __restrict__ qkv,
                                                        const float* __restrict__ cosT,
                                                        const float* __restrict__ sinT,
                                                        const float* __restrict__ qw,
                                                        const float* __restrict__ kw,
                                                        __bf16* __restrict__ Qo,
                                                        __bf16* __restrict__ Ko,
                                                        __bf16* __restrict__ VTo) {
  int s = blockIdx.x, b = blockIdx.y;
  int wid = threadIdx.x >> 6, lane = threadIdx.x & 63;
  const float* rowp = qkv + (size_t)(b * S_ + s) * NQKV_;
  float c = cosT[s * HD_ + lane];
  float sn = sinT[s * HD_ + lane];
#pragma unroll
  for (int it = 0; it < 5; it++) {
    int hh = it * 4 + wid; // 0..15 q heads, 16..19 k heads
    float v = rowp[hh * 64 + lane];
    float ss = v * v;
#pragma unroll
    for (int off = 1; off < 64; off <<= 1) ss += __shfl_xor(ss, off);
    float rs = rsqrtf(ss * (1.0f / 64.0f) + 1e-6f);
    const float* w = (hh < 16) ? qw : kw;
    float nv = v * rs * w[lane];
    float other = __shfl_xor(nv, 32);
    float rot = (lane < 32) ? -other : other; // rotate_half
    float outv = nv * c + rot * sn;
    if (hh < 16)
      Qo[(((size_t)b * NH_ + hh) * S_ + s) * HD_ + lane] = (__bf16)outv;
    else
      Ko[(((size_t)b * NKV_ + (hh - 16)) * S_ + s) * HD_ + lane] = (__bf16)outv;
  }
  {
    float v = rowp[(20 + wid) * 64 + lane];
    VTo[(((size_t)b * NKV_ + wid) * HD_ + lane) * S_ + s] = (__bf16)v;
  }
}

// ---------------- kernel: flash attention (causal, GQA), balanced pairing ----------------
// grid (S/128, NH, B), block 512 (8 waves). Waves 0-3 -> q-tile x, waves 4-7 -> q-tile 31-x.
// S^T orientation (A=K, B=Q): per-lane score regs are contiguous in kv for one q column,
// so P staging = 4 packed ds_write_b64 + 2 ds_read_b128 per tile. ALL loops statically
// unrolled (dynamic trip counts demote sf[] to scratch — round-2 lesson, VGPR 48 + spills).
// Fixed m=0 softmax: post-RMSNorm |q|=|k|=8 => |s|<=8, exp(s)<=2981, exact in fp32.
__global__ __launch_bounds__(512, 4) void attn_kernel(const __bf16* __restrict__ Q,
                                                      const __bf16* __restrict__ Kc,
                                                      const __bf16* __restrict__ VT,
                                                      __bf16* __restrict__ Ob) {
  int x = blockIdx.x, h = blockIdx.y, b = blockIdx.z;
  int wid = threadIdx.x >> 6, lane = threadIdx.x & 63;
  int l15 = lane & 15, quad = lane >> 4;
  int sub = wid & 3;
  int qt = (wid < 4) ? x : (31 - x);
  int q0 = qt * 64 + sub * 16;
  int kvh = h >> 2; // N_REP = 4
  const __bf16* Qh = Q + (((size_t)b * NH_ + h) * S_ + q0) * HD_;
  const __bf16* Kh = Kc + (((size_t)b * NKV_ + kvh) * S_) * HD_;
  const __bf16* Vh = VT + (((size_t)b * NKV_ + kvh) * HD_) * S_;
  __shared__ __align__(16) __bf16 Pst[8][16][72]; // per-wave P [q=16][kv=64+pad]
  __bf16 (*P)[72] = Pst[wid];

  bfx8 qf0, qf1;
  {
    const __bf16* qp = Qh + l15 * HD_ + quad * 8;
    qf0 = *(const bfx8*)qp;
    qf1 = *(const bfx8*)(qp + 32);
  }
  floatx4 oacc[4] = {};
  float ps = 0.f; // this lane's partial sum of exp over its kv slots (q = l15 fixed)
  int ntiles = qt + 1; // causal
  for (int kt = 0; kt < ntiles; kt++) {
    int kv0 = kt * 64;
    int dq = q0 - kv0; // >= 64 for all non-diagonal tiles -> mask never fires there
    // QK^T in S^T orientation: D[kv][q], row=quad*4+r=kv_rel, col=l15=q_rel
    floatx4 sf[4];
#pragma unroll
    for (int nt = 0; nt < 4; nt++) {
      const __bf16* kp = Kh + (size_t)(kv0 + nt * 16 + l15) * HD_ + quad * 8;
      bfx8 kf0 = *(const bfx8*)kp;
      bfx8 kf1 = *(const bfx8*)(kp + 32);
      floatx4 z = {0.f, 0.f, 0.f, 0.f};
      z = __builtin_amdgcn_mfma_f32_16x16x32_bf16(kf0, qf0, z, 0, 0, 0);
      sf[nt] = __builtin_amdgcn_mfma_f32_16x16x32_bf16(kf1, qf1, z, 0, 0, 0);
    }
    // V prefetch (independent; latency overlaps softmax)
    bfx8 vf0[4], vf1[4];
#pragma unroll
    for (int ot = 0; ot < 4; ot++) {
      const __bf16* vp = Vh + (size_t)(ot * 16 + l15) * S_ + kv0 + quad * 8;
      vf0[ot] = *(const bfx8*)vp;
      vf1[ot] = *(const bfx8*)(vp + 32);
    }
    // exp + branch-free causal mask + packed P write (P[q][kv])
#pragma unroll
    for (int nt = 0; nt < 4; nt++) {
      bfx4 pk;
#pragma unroll
      for (int r = 0; r < 4; r++) {
        int kvrel = nt * 16 + quad * 4 + r;
        float p = __expf(sf[nt][r] * 0.125f); // 1/sqrt(64)
        p = (kvrel - l15 > dq) ? 0.f : p;
        ps += p;
        pk[r] = (__bf16)p;
      }
      *(bfx4*)&P[l15][nt * 16 + quad * 4] = pk;
    }
    // P -> A-fragment (compiler inserts the lgkmcnt RAW wait)
    bfx8 pa0 = *(const bfx8*)&P[l15][quad * 8];
    bfx8 pa1 = *(const bfx8*)&P[l15][32 + quad * 8];
#pragma unroll
    for (int ot = 0; ot < 4; ot++) {
      oacc[ot] = __builtin_amdgcn_mfma_f32_16x16x32_bf16(pa0, vf0[ot], oacc[ot], 0, 0, 0);
      oacc[ot] = __builtin_amdgcn_mfma_f32_16x16x32_bf16(pa1, vf1[ot], oacc[ot], 0, 0, 0);
    }
  }
  // reduce l(q) across the 4 quads (lanes sharing l15)
  ps += __shfl_xor(ps, 16);
  ps += __shfl_xor(ps, 32);
  // output rows are q = quad*4+r; fetch l for that row from lane (quad*4+r)
  float rl[4];
#pragma unroll
  for (int r = 0; r < 4; r++) rl[r] = 1.0f / __shfl(ps, quad * 4 + r);
#pragma unroll
  for (int ot = 0; ot < 4; ot++)
#pragma unroll
    for (int r = 0; r < 4; r++) {
      float val = oacc[ot][r] * rl[r];
      Ob[((size_t)b * S_ + q0 + quad * 4 + r) * HQ_ + h * HD_ + ot * 16 + l15] = (__bf16)val;
    }
}

extern "C" void kernel_launch(void* const* d_in, const int* in_sizes, int n_in,
                              void* d_out, int out_size, void* d_ws, size_t ws_size,
                              hipStream_t stream) {
  const float* x   = (const float*)d_in[0];
  const float* cosT = (const float*)d_in[1];
  const float* sinT = (const float*)d_in[2];
  const float* wq  = (const float*)d_in[3];
  const float* wk  = (const float*)d_in[4];
  const float* wv  = (const float*)d_in[5];
  const float* wo  = (const float*)d_in[6];
  const float* qw  = (const float*)d_in[7];
  const float* kw  = (const float*)d_in[8];
  float* out = (float*)d_out;

  char* w = (char*)d_ws;
  __bf16* xbf   = (__bf16*)(w);                        // 16,777,216
  __bf16* wqkvT = (__bf16*)(w + 16777216);             //  6,291,456
  __bf16* woT   = (__bf16*)(w + 23068672);             //  4,194,304
  float*  qkv   = (float*) (w + 27262976);             // 25,165,824
  __bf16* Qb    = (__bf16*)(w + 52428800);             //  8,388,608
  __bf16* Kb    = (__bf16*)(w + 60817408);             //  2,097,152
  __bf16* VTb   = (__bf16*)(w + 62914560);             //  2,097,152
  __bf16* attn  = (__bf16*)(w + 65011712);             //  8,388,608 (end 73,400,320)

  cast_f32_bf16<<<(M_ * H_ / 4 + 255) / 256, 256, 0, stream>>>(x, xbf, M_ * H_ / 4);
  dim3 tb(32, 8);
  transpose_cast<<<dim3(1024 / 32, 2048 / 32), tb, 0, stream>>>(wq, wqkvT, 2048, 1024, 0,    2048);
  transpose_cast<<<dim3(256 / 32, 2048 / 32),  tb, 0, stream>>>(wk, wqkvT, 2048, 256,  1024, 2048);
  transpose_cast<<<dim3(256 / 32, 2048 / 32),  tb, 0, stream>>>(wv, wqkvT, 2048, 256,  1280, 2048);
  transpose_cast<<<dim3(2048 / 32, 1024 / 32), tb, 0, stream>>>(wo, woT,   1024, 2048, 0,    1024);
  gemm_bf16_f32<<<dim3(NQKV_ / 128, M_ / 128), 256, 0, stream>>>(xbf, wqkvT, qkv, M_, NQKV_, H_);
  norm_rope_kernel<<<dim3(S_, B_), 256, 0, stream>>>(qkv, cosT, sinT, qw, kw, Qb, Kb, VTb);
  attn_kernel<<<dim3(S_ / 128, NH_, B_), 512, 0, stream>>>(Qb, Kb, VTb, attn);
  gemm_bf16_f32<<<dim3(H_ / 128, M_ / 128), 256, 0, stream>>>(attn, woT, out, M_, H_, HQ_);
}

// Round 4
// 291.887 us; speedup vs baseline: 1.1118x; 1.1118x over previous
//
#include <hip/hip_runtime.h>

typedef float floatx4 __attribute__((ext_vector_type(4)));
typedef __bf16 bfx8 __attribute__((ext_vector_type(8)));
typedef __bf16 bfx4 __attribute__((ext_vector_type(4)));

// Problem constants
constexpr int B_ = 2, S_ = 2048, H_ = 2048, NH_ = 16, NKV_ = 4, HD_ = 64;
constexpr int M_ = B_ * S_;               // 4096 rows
constexpr int NQKV_ = NH_ * HD_ + 2 * NKV_ * HD_; // 1536
constexpr int HQ_ = NH_ * HD_;            // 1024
// Padded pitches (break 4KB/2KB row strides -> memory-channel aliasing; round-3 lesson:
// 4KB-stride lane patterns serialize on one channel, ~3600 stall cyc/iter in attn)
constexpr int XP_ = 2056;  // xbf / wqkvT pitch (K=2048 +8)
constexpr int AP_ = 1032;  // attn-out / woT pitch (K=1024 +8)
constexpr int VP_ = 2056;  // V-transposed pitch (S=2048 +8)

// ---------------- fp32 -> bf16 cast into padded-pitch buffer ----------------
__global__ __launch_bounds__(256) void cast_f32_bf16_pad(const float* __restrict__ src,
                                                         __bf16* __restrict__ dst) {
  int row = blockIdx.x;
  const float4* s = (const float4*)(src + (size_t)row * H_);
  __bf16* d = dst + (size_t)row * XP_;
#pragma unroll
  for (int i = 0; i < 2; i++) {
    int c = i * 256 + threadIdx.x; // 0..511
    float4 v = s[c];
    bfx4 o;
    o[0] = (__bf16)v.x; o[1] = (__bf16)v.y; o[2] = (__bf16)v.z; o[3] = (__bf16)v.w;
    *(bfx4*)(d + c * 4) = o;
  }
}

// ---------------- transpose + cast: dst[n+off][k] = src[k][n] ----------------
__global__ __launch_bounds__(256) void transpose_cast(const float* __restrict__ src,
                                                      __bf16* __restrict__ dst,
                                                      int K, int N, int dstOff, int dstPitch) {
  __shared__ float tile[32][33];
  int n0 = blockIdx.x * 32, k0 = blockIdx.y * 32;
  int tx = threadIdx.x, ty = threadIdx.y; // block (32,8)
#pragma unroll
  for (int r = 0; r < 32; r += 8)
    tile[ty + r][tx] = src[(size_t)(k0 + ty + r) * N + n0 + tx];
  __syncthreads();
#pragma unroll
  for (int r = 0; r < 32; r += 8)
    dst[(size_t)(n0 + ty + r + dstOff) * dstPitch + k0 + tx] = (__bf16)tile[tx][ty + r];
}

// ---------------- bf16 MFMA GEMM. A: MxK (lda), Bt: NxK (ldb), C: MxN fp32 (ldc)
__global__ __launch_bounds__(256) void gemm_bf16_f32(const __bf16* __restrict__ A,
                                                     const __bf16* __restrict__ Bt,
                                                     float* __restrict__ C,
                                                     int M, int N, int K,
                                                     int lda, int ldb, int ldc) {
  __shared__ __align__(16) __bf16 As[128][72];
  __shared__ __align__(16) __bf16 Bs[128][72];
  int wid = threadIdx.x >> 6, lane = threadIdx.x & 63;
  int l15 = lane & 15, quad = lane >> 4;
  int wm = (wid >> 1) * 64, wn = (wid & 1) * 64;
  int m0 = blockIdx.y * 128, n0 = blockIdx.x * 128;
  floatx4 acc[4][4] = {};
  for (int kb = 0; kb < K; kb += 64) {
#pragma unroll
    for (int i = 0; i < 4; i++) {
      int c = i * 256 + threadIdx.x;
      int r = c >> 3, col = (c & 7) * 8;
      *(bfx8*)&As[r][col] = *(const bfx8*)&A[(size_t)(m0 + r) * lda + kb + col];
      *(bfx8*)&Bs[r][col] = *(const bfx8*)&Bt[(size_t)(n0 + r) * ldb + kb + col];
    }
    __syncthreads();
#pragma unroll
    for (int kk = 0; kk < 64; kk += 32) {
      bfx8 af[4], bfr[4];
#pragma unroll
      for (int mi = 0; mi < 4; mi++)
        af[mi] = *(const bfx8*)&As[wm + mi * 16 + l15][kk + quad * 8];
#pragma unroll
      for (int ni = 0; ni < 4; ni++)
        bfr[ni] = *(const bfx8*)&Bs[wn + ni * 16 + l15][kk + quad * 8];
#pragma unroll
      for (int mi = 0; mi < 4; mi++)
#pragma unroll
        for (int ni = 0; ni < 4; ni++)
          acc[mi][ni] = __builtin_amdgcn_mfma_f32_16x16x32_bf16(af[mi], bfr[ni], acc[mi][ni], 0, 0, 0);
    }
    __syncthreads();
  }
#pragma unroll
  for (int mi = 0; mi < 4; mi++)
#pragma unroll
    for (int ni = 0; ni < 4; ni++) {
      int row = m0 + wm + mi * 16 + quad * 4;
      int coln = n0 + wn + ni * 16 + l15;
#pragma unroll
      for (int r = 0; r < 4; r++)
        C[(size_t)(row + r) * ldc + coln] = acc[mi][ni][r];
    }
}

// ---------------- RMSNorm + RoPE on q/k, cast+layout for attention ----------------
__global__ __launch_bounds__(256) void norm_rope_kernel(const float* __restrict__ qkv,
                                                        const float* __restrict__ cosT,
                                                        const float* __restrict__ sinT,
                                                        const float* __restrict__ qw,
                                                        const float* __restrict__ kw,
                                                        __bf16* __restrict__ Qo,
                                                        __bf16* __restrict__ Ko,
                                                        __bf16* __restrict__ VTo) {
  int s = blockIdx.x, b = blockIdx.y;
  int wid = threadIdx.x >> 6, lane = threadIdx.x & 63;
  const float* rowp = qkv + (size_t)(b * S_ + s) * NQKV_;
  float c = cosT[s * HD_ + lane];
  float sn = sinT[s * HD_ + lane];
#pragma unroll
  for (int it = 0; it < 5; it++) {
    int hh = it * 4 + wid; // 0..15 q heads, 16..19 k heads
    float v = rowp[hh * 64 + lane];
    float ss = v * v;
#pragma unroll
    for (int off = 1; off < 64; off <<= 1) ss += __shfl_xor(ss, off);
    float rs = rsqrtf(ss * (1.0f / 64.0f) + 1e-6f);
    const float* w = (hh < 16) ? qw : kw;
    float nv = v * rs * w[lane];
    float other = __shfl_xor(nv, 32);
    float rot = (lane < 32) ? -other : other; // rotate_half
    float outv = nv * c + rot * sn;
    if (hh < 16)
      Qo[(((size_t)b * NH_ + hh) * S_ + s) * HD_ + lane] = (__bf16)outv;
    else
      Ko[(((size_t)b * NKV_ + (hh - 16)) * S_ + s) * HD_ + lane] = (__bf16)outv;
  }
  {
    float v = rowp[(20 + wid) * 64 + lane];
    VTo[(((size_t)b * NKV_ + wid) * HD_ + lane) * VP_ + s] = (__bf16)v;
  }
}

// ---------------- flash attention (causal, GQA), balanced pairing ----------------
// grid (S/128, NH, B), block 512 (8 waves). Waves 0-3 -> q-tile x, waves 4-7 -> q-tile 31-x.
// S^T orientation (A=K, B=Q). Fixed m=0 softmax (post-RMSNorm |q|=|k|=8 => |s|<=8).
// Cross-iteration K-register prefetch; V loads issue early and overlap exp+LDS.
__global__ __launch_bounds__(512, 4) void attn_kernel(const __bf16* __restrict__ Q,
                                                      const __bf16* __restrict__ Kc,
                                                      const __bf16* __restrict__ VT,
                                                      __bf16* __restrict__ Ob) {
  int x = blockIdx.x, h = blockIdx.y, b = blockIdx.z;
  int wid = threadIdx.x >> 6, lane = threadIdx.x & 63;
  int l15 = lane & 15, quad = lane >> 4;
  int sub = wid & 3;
  int qt = (wid < 4) ? x : (31 - x);
  int q0 = qt * 64 + sub * 16;
  int kvh = h >> 2; // N_REP = 4
  const __bf16* Qh = Q + (((size_t)b * NH_ + h) * S_ + q0) * HD_;
  const __bf16* Kh = Kc + ((size_t)b * NKV_ + kvh) * S_ * HD_;
  const __bf16* Vh = VT + ((size_t)b * NKV_ + kvh) * (size_t)HD_ * VP_;
  __shared__ __align__(16) __bf16 Pst[8][16][72]; // per-wave P [q=16][kv=64+pad]
  __bf16 (*P)[72] = Pst[wid];

  bfx8 qf0, qf1;
  {
    const __bf16* qp = Qh + l15 * HD_ + quad * 8;
    qf0 = *(const bfx8*)qp;
    qf1 = *(const bfx8*)(qp + 32);
  }
  floatx4 oacc[4] = {};
  float ps = 0.f;
  int ntiles = qt + 1; // causal
  // preload K tile 0
  bfx8 kc0[4], kc1[4];
#pragma unroll
  for (int nt = 0; nt < 4; nt++) {
    const __bf16* kp = Kh + (size_t)(nt * 16 + l15) * HD_ + quad * 8;
    kc0[nt] = *(const bfx8*)kp;
    kc1[nt] = *(const bfx8*)(kp + 32);
  }
  for (int kt = 0; kt < ntiles; kt++) {
    int kv0 = kt * 64;
    int dq = q0 - kv0; // >= 64 on non-diagonal tiles -> mask never fires there
    int kvn = (kt + 1 < ntiles) ? kv0 + 64 : 0; // clamp: last-iter prefetch harmless
    // prefetch next K tile (global latency overlaps this whole iteration)
    bfx8 kn0[4], kn1[4];
#pragma unroll
    for (int nt = 0; nt < 4; nt++) {
      const __bf16* kp = Kh + (size_t)(kvn + nt * 16 + l15) * HD_ + quad * 8;
      kn0[nt] = *(const bfx8*)kp;
      kn1[nt] = *(const bfx8*)(kp + 32);
    }
    // QK^T in S^T orientation: D[kv][q], row=quad*4+r=kv_rel, col=l15=q_rel
    floatx4 sf[4];
#pragma unroll
    for (int nt = 0; nt < 4; nt++) {
      floatx4 z = {0.f, 0.f, 0.f, 0.f};
      z = __builtin_amdgcn_mfma_f32_16x16x32_bf16(kc0[nt], qf0, z, 0, 0, 0);
      sf[nt] = __builtin_amdgcn_mfma_f32_16x16x32_bf16(kc1[nt], qf1, z, 0, 0, 0);
    }
    // V loads (padded pitch VP_ kills 4KB channel aliasing); latency overlaps exp
    bfx8 vf0[4], vf1[4];
#pragma unroll
    for (int ot = 0; ot < 4; ot++) {
      const __bf16* vp = Vh + (size_t)(ot * 16 + l15) * VP_ + kv0 + quad * 8;
      vf0[ot] = *(const bfx8*)vp;
      vf1[ot] = *(const bfx8*)(vp + 32);
    }
    // exp + branch-free causal mask + packed P write (P[q][kv])
#pragma unroll
    for (int nt = 0; nt < 4; nt++) {
      bfx4 pk;
#pragma unroll
      for (int r = 0; r < 4; r++) {
        int kvrel = nt * 16 + quad * 4 + r;
        float p = __expf(sf[nt][r] * 0.125f); // 1/sqrt(64)
        p = (kvrel - l15 > dq) ? 0.f : p;
        ps += p;
        pk[r] = (__bf16)p;
      }
      *(bfx4*)&P[l15][nt * 16 + quad * 4] = pk;
    }
    // P -> A-fragment (compiler inserts the lgkmcnt RAW wait)
    bfx8 pa0 = *(const bfx8*)&P[l15][quad * 8];
    bfx8 pa1 = *(const bfx8*)&P[l15][32 + quad * 8];
#pragma unroll
    for (int ot = 0; ot < 4; ot++) {
      oacc[ot] = __builtin_amdgcn_mfma_f32_16x16x32_bf16(pa0, vf0[ot], oacc[ot], 0, 0, 0);
      oacc[ot] = __builtin_amdgcn_mfma_f32_16x16x32_bf16(pa1, vf1[ot], oacc[ot], 0, 0, 0);
    }
    // rotate prefetched K into current
#pragma unroll
    for (int nt = 0; nt < 4; nt++) { kc0[nt] = kn0[nt]; kc1[nt] = kn1[nt]; }
  }
  // reduce l(q) across the 4 quads (lanes sharing l15)
  ps += __shfl_xor(ps, 16);
  ps += __shfl_xor(ps, 32);
  float rl[4];
#pragma unroll
  for (int r = 0; r < 4; r++) rl[r] = 1.0f / __shfl(ps, quad * 4 + r);
#pragma unroll
  for (int ot = 0; ot < 4; ot++)
#pragma unroll
    for (int r = 0; r < 4; r++) {
      float val = oacc[ot][r] * rl[r];
      Ob[((size_t)b * S_ + q0 + quad * 4 + r) * AP_ + h * HD_ + ot * 16 + l15] = (__bf16)val;
    }
}

extern "C" void kernel_launch(void* const* d_in, const int* in_sizes, int n_in,
                              void* d_out, int out_size, void* d_ws, size_t ws_size,
                              hipStream_t stream) {
  const float* x   = (const float*)d_in[0];
  const float* cosT = (const float*)d_in[1];
  const float* sinT = (const float*)d_in[2];
  const float* wq  = (const float*)d_in[3];
  const float* wk  = (const float*)d_in[4];
  const float* wv  = (const float*)d_in[5];
  const float* wo  = (const float*)d_in[6];
  const float* qw  = (const float*)d_in[7];
  const float* kw  = (const float*)d_in[8];
  float* out = (float*)d_out;

  char* w = (char*)d_ws;
  __bf16* xbf   = (__bf16*)(w);                        // 4096*2056*2 = 16,842,752
  __bf16* wqkvT = (__bf16*)(w + 16842752);             // 1536*2056*2 =  6,316,032
  __bf16* woT   = (__bf16*)(w + 23158784);             // 2048*1032*2 =  4,227,072
  float*  qkv   = (float*) (w + 27385856);             // 4096*1536*4 = 25,165,824
  __bf16* attnO = (__bf16*)(w + 27385856);             // aliases qkv (qkv dead after norm_rope)
  __bf16* Qb    = (__bf16*)(w + 52551680);             //  8,388,608
  __bf16* Kb    = (__bf16*)(w + 60940288);             //  2,097,152
  __bf16* VTb   = (__bf16*)(w + 63037440);             // 2*4*64*2056*2 = 2,105,344 (end 65,142,784)

  cast_f32_bf16_pad<<<M_, 256, 0, stream>>>(x, xbf);
  dim3 tb(32, 8);
  transpose_cast<<<dim3(1024 / 32, 2048 / 32), tb, 0, stream>>>(wq, wqkvT, 2048, 1024, 0,    XP_);
  transpose_cast<<<dim3(256 / 32, 2048 / 32),  tb, 0, stream>>>(wk, wqkvT, 2048, 256,  1024, XP_);
  transpose_cast<<<dim3(256 / 32, 2048 / 32),  tb, 0, stream>>>(wv, wqkvT, 2048, 256,  1280, XP_);
  transpose_cast<<<dim3(2048 / 32, 1024 / 32), tb, 0, stream>>>(wo, woT,   1024, 2048, 0,    AP_);
  gemm_bf16_f32<<<dim3(NQKV_ / 128, M_ / 128), 256, 0, stream>>>(xbf, wqkvT, qkv, M_, NQKV_, H_, XP_, XP_, NQKV_);
  norm_rope_kernel<<<dim3(S_, B_), 256, 0, stream>>>(qkv, cosT, sinT, qw, kw, Qb, Kb, VTb);
  attn_kernel<<<dim3(S_ / 128, NH_, B_), 512, 0, stream>>>(Qb, Kb, VTb, attnO);
  gemm_bf16_f32<<<dim3(H_ / 128, M_ / 128), 256, 0, stream>>>(attnO, woT, out, M_, H_, HQ_, AP_, AP_, H_);
}

// Round 5
// 246.077 us; speedup vs baseline: 1.3188x; 1.1862x over previous
//
#include <hip/hip_runtime.h>

typedef float floatx4 __attribute__((ext_vector_type(4)));
typedef __bf16 bfx8 __attribute__((ext_vector_type(8)));
typedef __bf16 bfx4 __attribute__((ext_vector_type(4)));

// Problem constants
constexpr int B_ = 2, S_ = 2048, H_ = 2048, NH_ = 16, NKV_ = 4, HD_ = 64;
constexpr int M_ = B_ * S_;               // 4096 rows
constexpr int NQKV_ = NH_ * HD_ + 2 * NKV_ * HD_; // 1536
constexpr int HQ_ = NH_ * HD_;            // 1024
// Padded pitches (break 4KB/2KB row strides -> channel aliasing; round-4 win)
constexpr int XP_ = 2056;  // xbf / wqkvT pitch
constexpr int AP_ = 1032;  // attn-out / woT pitch
constexpr int VP_ = 2056;  // V-transposed pitch

// ---------------- fp32 -> bf16 cast into padded-pitch buffer ----------------
__global__ __launch_bounds__(256) void cast_f32_bf16_pad(const float* __restrict__ src,
                                                         __bf16* __restrict__ dst) {
  int row = blockIdx.x;
  const float4* s = (const float4*)(src + (size_t)row * H_);
  __bf16* d = dst + (size_t)row * XP_;
#pragma unroll
  for (int i = 0; i < 2; i++) {
    int c = i * 256 + threadIdx.x;
    float4 v = s[c];
    bfx4 o;
    o[0] = (__bf16)v.x; o[1] = (__bf16)v.y; o[2] = (__bf16)v.z; o[3] = (__bf16)v.w;
    *(bfx4*)(d + c * 4) = o;
  }
}

// ---------------- transpose + cast: dst[n+off][k] = src[k][n] ----------------
__global__ __launch_bounds__(256) void transpose_cast(const float* __restrict__ src,
                                                      __bf16* __restrict__ dst,
                                                      int K, int N, int dstOff, int dstPitch) {
  __shared__ float tile[32][33];
  int n0 = blockIdx.x * 32, k0 = blockIdx.y * 32;
  int tx = threadIdx.x, ty = threadIdx.y; // block (32,8)
#pragma unroll
  for (int r = 0; r < 32; r += 8)
    tile[ty + r][tx] = src[(size_t)(k0 + ty + r) * N + n0 + tx];
  __syncthreads();
#pragma unroll
  for (int r = 0; r < 32; r += 8)
    dst[(size_t)(n0 + ty + r + dstOff) * dstPitch + k0 + tx] = (__bf16)tile[tx][ty + r];
}

// ---------------- bf16 MFMA GEMM. A: MxK (lda), Bt: NxK (ldb), C: MxN fp32 (ldc)
__global__ __launch_bounds__(256) void gemm_bf16_f32(const __bf16* __restrict__ A,
                                                     const __bf16* __restrict__ Bt,
                                                     float* __restrict__ C,
                                                     int M, int N, int K,
                                                     int lda, int ldb, int ldc) {
  __shared__ __align__(16) __bf16 As[128][72];
  __shared__ __align__(16) __bf16 Bs[128][72];
  int wid = threadIdx.x >> 6, lane = threadIdx.x & 63;
  int l15 = lane & 15, quad = lane >> 4;
  int wm = (wid >> 1) * 64, wn = (wid & 1) * 64;
  int m0 = blockIdx.y * 128, n0 = blockIdx.x * 128;
  floatx4 acc[4][4] = {};
  for (int kb = 0; kb < K; kb += 64) {
#pragma unroll
    for (int i = 0; i < 4; i++) {
      int c = i * 256 + threadIdx.x;
      int r = c >> 3, col = (c & 7) * 8;
      *(bfx8*)&As[r][col] = *(const bfx8*)&A[(size_t)(m0 + r) * lda + kb + col];
      *(bfx8*)&Bs[r][col] = *(const bfx8*)&Bt[(size_t)(n0 + r) * ldb + kb + col];
    }
    __syncthreads();
#pragma unroll
    for (int kk = 0; kk < 64; kk += 32) {
      bfx8 af[4], bfr[4];
#pragma unroll
      for (int mi = 0; mi < 4; mi++)
        af[mi] = *(const bfx8*)&As[wm + mi * 16 + l15][kk + quad * 8];
#pragma unroll
      for (int ni = 0; ni < 4; ni++)
        bfr[ni] = *(const bfx8*)&Bs[wn + ni * 16 + l15][kk + quad * 8];
#pragma unroll
      for (int mi = 0; mi < 4; mi++)
#pragma unroll
        for (int ni = 0; ni < 4; ni++)
          acc[mi][ni] = __builtin_amdgcn_mfma_f32_16x16x32_bf16(af[mi], bfr[ni], acc[mi][ni], 0, 0, 0);
    }
    __syncthreads();
  }
#pragma unroll
  for (int mi = 0; mi < 4; mi++)
#pragma unroll
    for (int ni = 0; ni < 4; ni++) {
      int row = m0 + wm + mi * 16 + quad * 4;
      int coln = n0 + wn + ni * 16 + l15;
#pragma unroll
      for (int r = 0; r < 4; r++)
        C[(size_t)(row + r) * ldc + coln] = acc[mi][ni][r];
    }
}

// ---------------- RMSNorm + RoPE on q/k, cast+layout for attention ----------------
__global__ __launch_bounds__(256) void norm_rope_kernel(const float* __restrict__ qkv,
                                                        const float* __restrict__ cosT,
                                                        const float* __restrict__ sinT,
                                                        const float* __restrict__ qw,
                                                        const float* __restrict__ kw,
                                                        __bf16* __restrict__ Qo,
                                                        __bf16* __restrict__ Ko,
                                                        __bf16* __restrict__ VTo) {
  int s = blockIdx.x, b = blockIdx.y;
  int wid = threadIdx.x >> 6, lane = threadIdx.x & 63;
  const float* rowp = qkv + (size_t)(b * S_ + s) * NQKV_;
  float c = cosT[s * HD_ + lane];
  float sn = sinT[s * HD_ + lane];
#pragma unroll
  for (int it = 0; it < 5; it++) {
    int hh = it * 4 + wid; // 0..15 q heads, 16..19 k heads
    float v = rowp[hh * 64 + lane];
    float ss = v * v;
#pragma unroll
    for (int off = 1; off < 64; off <<= 1) ss += __shfl_xor(ss, off);
    float rs = rsqrtf(ss * (1.0f / 64.0f) + 1e-6f);
    const float* w = (hh < 16) ? qw : kw;
    float nv = v * rs * w[lane];
    float other = __shfl_xor(nv, 32);
    float rot = (lane < 32) ? -other : other; // rotate_half
    float outv = nv * c + rot * sn;
    if (hh < 16)
      Qo[(((size_t)b * NH_ + hh) * S_ + s) * HD_ + lane] = (__bf16)outv;
    else
      Ko[(((size_t)b * NKV_ + (hh - 16)) * S_ + s) * HD_ + lane] = (__bf16)outv;
  }
  {
    float v = rowp[(20 + wid) * 64 + lane];
    VTo[(((size_t)b * NKV_ + wid) * HD_ + lane) * VP_ + s] = (__bf16)v;
  }
}

// ---------------- flash attention (causal, GQA), block-cooperative LDS staging ----------
// grid (32, NH, B), block 256 (4 waves) = one 64-row q-tile; wave w = rows [w*16, w*16+16).
// K/V tiles staged in LDS once per block-iteration (coalesced 1KB loads, shared by 4 waves)
// -- kills the round-4 L1-transaction bottleneck (16 sparse segments/instr, 8x redundant).
// Register-prefetch double buffer hides global latency. Triangle balance: qt swizzled so a
// CU's resident set {c, c+256, c+512, c+768} (px same, h^8, b^1) holds two qt=u and two
// qt=31-u blocks -> exactly 66 kv-iterations per CU-set.
// Fixed m=0 softmax: post-RMSNorm |q|=|k|=8 => |s|<=8, exp(s)<=2981, exact in fp32.
__global__ __launch_bounds__(256, 4) void attn_kernel(const __bf16* __restrict__ Q,
                                                      const __bf16* __restrict__ Kc,
                                                      const __bf16* __restrict__ VT,
                                                      __bf16* __restrict__ Ob) {
  int px = blockIdx.x, h = blockIdx.y, b = blockIdx.z;
  int u = (px + 2 * (h & 7)) & 31;
  int qt = (((h >> 3) ^ b) & 1) ? (31 - u) : u;
  int wid = threadIdx.x >> 6, lane = threadIdx.x & 63;
  int l15 = lane & 15, quad = lane >> 4;
  int q0 = qt * 64 + wid * 16;
  int kvh = h >> 2; // N_REP = 4
  const __bf16* Qh = Q + (((size_t)b * NH_ + h) * S_ + q0) * HD_;
  const __bf16* Kh = Kc + ((size_t)b * NKV_ + kvh) * S_ * HD_;
  const __bf16* Vh = VT + ((size_t)b * NKV_ + kvh) * (size_t)HD_ * VP_;
  __shared__ __align__(16) __bf16 Ks[64][72]; // [kv][hd]
  __shared__ __align__(16) __bf16 Vs[64][72]; // [hd][kv]
  __shared__ __align__(16) __bf16 Pst[4][16][72];
  __bf16 (*P)[72] = Pst[wid];

  // staging slice for this thread: 2 rows (r, r+32), 16B each
  int srow = threadIdx.x >> 3;         // 0..31
  int scol = (threadIdx.x & 7) * 8;    // element offset 0..56

  bfx8 qf0, qf1;
  {
    const __bf16* qp = Qh + l15 * HD_ + quad * 8;
    qf0 = *(const bfx8*)qp;
    qf1 = *(const bfx8*)(qp + 32);
  }
  floatx4 oacc[4] = {};
  float ps = 0.f;
  int ntiles = qt + 1; // causal, block-uniform
  // prologue: prefetch tile 0 into regs
  bfx8 kpre0, kpre1, vpre0, vpre1;
  kpre0 = *(const bfx8*)&Kh[(size_t)srow * HD_ + scol];
  kpre1 = *(const bfx8*)&Kh[(size_t)(srow + 32) * HD_ + scol];
  vpre0 = *(const bfx8*)&Vh[(size_t)srow * VP_ + scol];
  vpre1 = *(const bfx8*)&Vh[(size_t)(srow + 32) * VP_ + scol];
  for (int kt = 0; kt < ntiles; kt++) {
    int kv0 = kt * 64;
    int dq = q0 - kv0; // >=64 on non-diagonal tiles -> mask never fires there
    __syncthreads(); // previous compute done reading LDS
    *(bfx8*)&Ks[srow][scol] = kpre0;
    *(bfx8*)&Ks[srow + 32][scol] = kpre1;
    *(bfx8*)&Vs[srow][scol] = vpre0;
    *(bfx8*)&Vs[srow + 32][scol] = vpre1;
    __syncthreads(); // staged tile visible
    if (kt + 1 < ntiles) { // block-uniform branch; latency overlaps compute below
      int kn = kv0 + 64;
      kpre0 = *(const bfx8*)&Kh[(size_t)(kn + srow) * HD_ + scol];
      kpre1 = *(const bfx8*)&Kh[(size_t)(kn + srow + 32) * HD_ + scol];
      vpre0 = *(const bfx8*)&Vh[(size_t)srow * VP_ + kn + scol];
      vpre1 = *(const bfx8*)&Vh[(size_t)(srow + 32) * VP_ + kn + scol];
    }
    // QK^T, S^T orientation: D[kv][q], row=nt*16+quad*4+r=kv_rel, col=l15=q_rel
    floatx4 sf[4];
#pragma unroll
    for (int nt = 0; nt < 4; nt++) {
      bfx8 kf0 = *(const bfx8*)&Ks[nt * 16 + l15][quad * 8];
      bfx8 kf1 = *(const bfx8*)&Ks[nt * 16 + l15][32 + quad * 8];
      floatx4 z = {0.f, 0.f, 0.f, 0.f};
      z = __builtin_amdgcn_mfma_f32_16x16x32_bf16(kf0, qf0, z, 0, 0, 0);
      sf[nt] = __builtin_amdgcn_mfma_f32_16x16x32_bf16(kf1, qf1, z, 0, 0, 0);
    }
    // exp + branch-free causal mask + packed P write (P[q][kv])
#pragma unroll
    for (int nt = 0; nt < 4; nt++) {
      bfx4 pk;
#pragma unroll
      for (int r = 0; r < 4; r++) {
        int kvrel = nt * 16 + quad * 4 + r;
        float p = __expf(sf[nt][r] * 0.125f); // 1/sqrt(64)
        p = (kvrel - l15 > dq) ? 0.f : p;
        ps += p;
        pk[r] = (__bf16)p;
      }
      *(bfx4*)&P[l15][nt * 16 + quad * 4] = pk;
    }
    // P -> A-fragment; V fragments from LDS (compiler inserts RAW lgkmcnt waits)
    bfx8 pa0 = *(const bfx8*)&P[l15][quad * 8];
    bfx8 pa1 = *(const bfx8*)&P[l15][32 + quad * 8];
#pragma unroll
    for (int ot = 0; ot < 4; ot++) {
      bfx8 vf0 = *(const bfx8*)&Vs[ot * 16 + l15][quad * 8];
      bfx8 vf1 = *(const bfx8*)&Vs[ot * 16 + l15][32 + quad * 8];
      oacc[ot] = __builtin_amdgcn_mfma_f32_16x16x32_bf16(pa0, vf0, oacc[ot], 0, 0, 0);
      oacc[ot] = __builtin_amdgcn_mfma_f32_16x16x32_bf16(pa1, vf1, oacc[ot], 0, 0, 0);
    }
  }
  // reduce l(q) across the 4 quads (lanes sharing l15)
  ps += __shfl_xor(ps, 16);
  ps += __shfl_xor(ps, 32);
  float rl[4];
#pragma unroll
  for (int r = 0; r < 4; r++) rl[r] = 1.0f / __shfl(ps, quad * 4 + r);
#pragma unroll
  for (int ot = 0; ot < 4; ot++)
#pragma unroll
    for (int r = 0; r < 4; r++) {
      float val = oacc[ot][r] * rl[r];
      Ob[((size_t)b * S_ + q0 + quad * 4 + r) * AP_ + h * HD_ + ot * 16 + l15] = (__bf16)val;
    }
}

extern "C" void kernel_launch(void* const* d_in, const int* in_sizes, int n_in,
                              void* d_out, int out_size, void* d_ws, size_t ws_size,
                              hipStream_t stream) {
  const float* x   = (const float*)d_in[0];
  const float* cosT = (const float*)d_in[1];
  const float* sinT = (const float*)d_in[2];
  const float* wq  = (const float*)d_in[3];
  const float* wk  = (const float*)d_in[4];
  const float* wv  = (const float*)d_in[5];
  const float* wo  = (const float*)d_in[6];
  const float* qw  = (const float*)d_in[7];
  const float* kw  = (const float*)d_in[8];
  float* out = (float*)d_out;

  char* w = (char*)d_ws;
  __bf16* xbf   = (__bf16*)(w);                        // 4096*2056*2 = 16,842,752
  __bf16* wqkvT = (__bf16*)(w + 16842752);             // 1536*2056*2 =  6,316,032
  __bf16* woT   = (__bf16*)(w + 23158784);             // 2048*1032*2 =  4,227,072
  float*  qkv   = (float*) (w + 27385856);             // 4096*1536*4 = 25,165,824
  __bf16* attnO = (__bf16*)(w + 27385856);             // aliases qkv (qkv dead after norm_rope)
  __bf16* Qb    = (__bf16*)(w + 52551680);             //  8,388,608
  __bf16* Kb    = (__bf16*)(w + 60940288);             //  2,097,152
  __bf16* VTb   = (__bf16*)(w + 63037440);             // 2*4*64*2056*2 = 2,105,344 (end 65,142,784)

  cast_f32_bf16_pad<<<M_, 256, 0, stream>>>(x, xbf);
  dim3 tb(32, 8);
  transpose_cast<<<dim3(1024 / 32, 2048 / 32), tb, 0, stream>>>(wq, wqkvT, 2048, 1024, 0,    XP_);
  transpose_cast<<<dim3(256 / 32, 2048 / 32),  tb, 0, stream>>>(wk, wqkvT, 2048, 256,  1024, XP_);
  transpose_cast<<<dim3(256 / 32, 2048 / 32),  tb, 0, stream>>>(wv, wqkvT, 2048, 256,  1280, XP_);
  transpose_cast<<<dim3(2048 / 32, 1024 / 32), tb, 0, stream>>>(wo, woT,   1024, 2048, 0,    AP_);
  gemm_bf16_f32<<<dim3(NQKV_ / 128, M_ / 128), 256, 0, stream>>>(xbf, wqkvT, qkv, M_, NQKV_, H_, XP_, XP_, NQKV_);
  norm_rope_kernel<<<dim3(S_, B_), 256, 0, stream>>>(qkv, cosT, sinT, qw, kw, Qb, Kb, VTb);
  attn_kernel<<<dim3(32, NH_, B_), 256, 0, stream>>>(Qb, Kb, VTb, attnO);
  gemm_bf16_f32<<<dim3(H_ / 128, M_ / 128), 256, 0, stream>>>(attnO, woT, out, M_, H_, HQ_, AP_, AP_, H_);
}

// Round 6
// 244.538 us; speedup vs baseline: 1.3271x; 1.0063x over previous
//
#include <hip/hip_runtime.h>

typedef float floatx4 __attribute__((ext_vector_type(4)));
typedef __bf16 bfx8 __attribute__((ext_vector_type(8)));
typedef __bf16 bfx4 __attribute__((ext_vector_type(4)));

// Problem constants
constexpr int B_ = 2, S_ = 2048, H_ = 2048, NH_ = 16, NKV_ = 4, HD_ = 64;
constexpr int M_ = B_ * S_;               // 4096 rows
constexpr int NQKV_ = NH_ * HD_ + 2 * NKV_ * HD_; // 1536
constexpr int HQ_ = NH_ * HD_;            // 1024
// Padded pitches (break 4KB/2KB row strides -> channel aliasing; round-4 win)
constexpr int XP_ = 2056;  // xbf / wqkvT pitch
constexpr int AP_ = 1032;  // attn-out / woT pitch
constexpr int VP_ = 2056;  // V-transposed pitch

#define GLB(p) ((const __attribute__((address_space(1))) void*)(p))
#define LDS(p) ((__attribute__((address_space(3))) void*)(p))

// ---------------- fp32 -> bf16 cast into padded-pitch buffer ----------------
__global__ __launch_bounds__(256) void cast_f32_bf16_pad(const float* __restrict__ src,
                                                         __bf16* __restrict__ dst) {
  int row = blockIdx.x;
  const float4* s = (const float4*)(src + (size_t)row * H_);
  __bf16* d = dst + (size_t)row * XP_;
#pragma unroll
  for (int i = 0; i < 2; i++) {
    int c = i * 256 + threadIdx.x;
    float4 v = s[c];
    bfx4 o;
    o[0] = (__bf16)v.x; o[1] = (__bf16)v.y; o[2] = (__bf16)v.z; o[3] = (__bf16)v.w;
    *(bfx4*)(d + c * 4) = o;
  }
}

// ---------------- transpose + cast: dst[n+off][k] = src[k][n] ----------------
__global__ __launch_bounds__(256) void transpose_cast(const float* __restrict__ src,
                                                      __bf16* __restrict__ dst,
                                                      int K, int N, int dstOff, int dstPitch) {
  __shared__ float tile[32][33];
  int n0 = blockIdx.x * 32, k0 = blockIdx.y * 32;
  int tx = threadIdx.x, ty = threadIdx.y; // block (32,8)
#pragma unroll
  for (int r = 0; r < 32; r += 8)
    tile[ty + r][tx] = src[(size_t)(k0 + ty + r) * N + n0 + tx];
  __syncthreads();
#pragma unroll
  for (int r = 0; r < 32; r += 8)
    dst[(size_t)(n0 + ty + r + dstOff) * dstPitch + k0 + tx] = (__bf16)tile[tx][ty + r];
}

// ---------------- bf16 MFMA GEMM, global_load_lds staging (m97 structure) ------------
// A: MxK (lda), Bt: NxK (ldb), C: MxN fp32 (ldc). 128x128 tile, BK=64, 4 waves 2x2.
// LDS unpadded (DMA dest = wave-uniform base + lane*16). XOR swizzle done on the SOURCE
// address: LDS group g at row r holds logical group g^(r&7) -> fragment reads spread all
// 8 bank-groups per 16-lane phase (2-way = free), staging needs no VALU repack at all.
__global__ __launch_bounds__(256) void gemm_bf16_f32(const __bf16* __restrict__ A,
                                                     const __bf16* __restrict__ Bt,
                                                     float* __restrict__ C,
                                                     int M, int N, int K,
                                                     int lda, int ldb, int ldc) {
  __shared__ __align__(16) __bf16 As[128 * 64];
  __shared__ __align__(16) __bf16 Bs[128 * 64];
  int wid = threadIdx.x >> 6, lane = threadIdx.x & 63;
  int l15 = lane & 15, quad = lane >> 4;
  int wm = (wid >> 1) * 64, wn = (wid & 1) * 64;
  int m0 = blockIdx.y * 128, n0 = blockIdx.x * 128;
  // staging: wave wid, instr j -> LDS rows [wid*32+j*8, +8); lane covers row +(lane>>3),
  // physical group lane&7, logical group (lane&7)^(row&7)
  int srow_off = lane >> 3;
  int gphys = lane & 7;
  floatx4 acc[4][4] = {};
  for (int kb = 0; kb < K; kb += 64) {
#pragma unroll
    for (int j = 0; j < 4; j++) {
      int rbase = wid * 32 + j * 8;
      int row = rbase + srow_off;
      int glog = gphys ^ (row & 7);
      const __bf16* ga = &A[(size_t)(m0 + row) * lda + kb + glog * 8];
      const __bf16* gb = &Bt[(size_t)(n0 + row) * ldb + kb + glog * 8];
      __builtin_amdgcn_global_load_lds(GLB(ga), LDS(&As[rbase * 64]), 16, 0, 0);
      __builtin_amdgcn_global_load_lds(GLB(gb), LDS(&Bs[rbase * 64]), 16, 0, 0);
    }
    __syncthreads(); // compiler emits vmcnt(0) drain before barrier
#pragma unroll
    for (int kk = 0; kk < 64; kk += 32) {
      int cgq = (kk >> 3) + quad; // logical 16B-group of this quad's fragment
      bfx8 af[4], bfr[4];
#pragma unroll
      for (int mi = 0; mi < 4; mi++) {
        int row = wm + mi * 16 + l15;
        af[mi] = *(const bfx8*)&As[row * 64 + (cgq ^ (row & 7)) * 8];
      }
#pragma unroll
      for (int ni = 0; ni < 4; ni++) {
        int row = wn + ni * 16 + l15;
        bfr[ni] = *(const bfx8*)&Bs[row * 64 + (cgq ^ (row & 7)) * 8];
      }
#pragma unroll
      for (int mi = 0; mi < 4; mi++)
#pragma unroll
        for (int ni = 0; ni < 4; ni++)
          acc[mi][ni] = __builtin_amdgcn_mfma_f32_16x16x32_bf16(af[mi], bfr[ni], acc[mi][ni], 0, 0, 0);
    }
    __syncthreads();
  }
#pragma unroll
  for (int mi = 0; mi < 4; mi++)
#pragma unroll
    for (int ni = 0; ni < 4; ni++) {
      int row = m0 + wm + mi * 16 + quad * 4;
      int coln = n0 + wn + ni * 16 + l15;
#pragma unroll
      for (int r = 0; r < 4; r++)
        C[(size_t)(row + r) * ldc + coln] = acc[mi][ni][r];
    }
}

// ---------------- RMSNorm + RoPE on q/k, cast+layout for attention ----------------
__global__ __launch_bounds__(256) void norm_rope_kernel(const float* __restrict__ qkv,
                                                        const float* __restrict__ cosT,
                                                        const float* __restrict__ sinT,
                                                        const float* __restrict__ qw,
                                                        const float* __restrict__ kw,
                                                        __bf16* __restrict__ Qo,
                                                        __bf16* __restrict__ Ko,
                                                        __bf16* __restrict__ VTo) {
  int s = blockIdx.x, b = blockIdx.y;
  int wid = threadIdx.x >> 6, lane = threadIdx.x & 63;
  const float* rowp = qkv + (size_t)(b * S_ + s) * NQKV_;
  float c = cosT[s * HD_ + lane];
  float sn = sinT[s * HD_ + lane];
#pragma unroll
  for (int it = 0; it < 5; it++) {
    int hh = it * 4 + wid; // 0..15 q heads, 16..19 k heads
    float v = rowp[hh * 64 + lane];
    float ss = v * v;
#pragma unroll
    for (int off = 1; off < 64; off <<= 1) ss += __shfl_xor(ss, off);
    float rs = rsqrtf(ss * (1.0f / 64.0f) + 1e-6f);
    const float* w = (hh < 16) ? qw : kw;
    float nv = v * rs * w[lane];
    float other = __shfl_xor(nv, 32);
    float rot = (lane < 32) ? -other : other; // rotate_half
    float outv = nv * c + rot * sn;
    if (hh < 16)
      Qo[(((size_t)b * NH_ + hh) * S_ + s) * HD_ + lane] = (__bf16)outv;
    else
      Ko[(((size_t)b * NKV_ + (hh - 16)) * S_ + s) * HD_ + lane] = (__bf16)outv;
  }
  {
    float v = rowp[(20 + wid) * 64 + lane];
    VTo[(((size_t)b * NKV_ + wid) * HD_ + lane) * VP_ + s] = (__bf16)v;
  }
}

// ---------------- flash attention (causal, GQA), block-cooperative LDS staging ----------
__global__ __launch_bounds__(256, 4) void attn_kernel(const __bf16* __restrict__ Q,
                                                      const __bf16* __restrict__ Kc,
                                                      const __bf16* __restrict__ VT,
                                                      __bf16* __restrict__ Ob) {
  int px = blockIdx.x, h = blockIdx.y, b = blockIdx.z;
  int u = (px + 2 * (h & 7)) & 31;
  int qt = (((h >> 3) ^ b) & 1) ? (31 - u) : u;
  int wid = threadIdx.x >> 6, lane = threadIdx.x & 63;
  int l15 = lane & 15, quad = lane >> 4;
  int q0 = qt * 64 + wid * 16;
  int kvh = h >> 2; // N_REP = 4
  const __bf16* Qh = Q + (((size_t)b * NH_ + h) * S_ + q0) * HD_;
  const __bf16* Kh = Kc + ((size_t)b * NKV_ + kvh) * S_ * HD_;
  const __bf16* Vh = VT + ((size_t)b * NKV_ + kvh) * (size_t)HD_ * VP_;
  __shared__ __align__(16) __bf16 Ks[64][72]; // [kv][hd]
  __shared__ __align__(16) __bf16 Vs[64][72]; // [hd][kv]
  __shared__ __align__(16) __bf16 Pst[4][16][72];
  __bf16 (*P)[72] = Pst[wid];

  int srow = threadIdx.x >> 3;         // 0..31
  int scol = (threadIdx.x & 7) * 8;    // element offset 0..56

  bfx8 qf0, qf1;
  {
    const __bf16* qp = Qh + l15 * HD_ + quad * 8;
    qf0 = *(const bfx8*)qp;
    qf1 = *(const bfx8*)(qp + 32);
  }
  floatx4 oacc[4] = {};
  float ps = 0.f;
  int ntiles = qt + 1; // causal, block-uniform
  bfx8 kpre0, kpre1, vpre0, vpre1;
  kpre0 = *(const bfx8*)&Kh[(size_t)srow * HD_ + scol];
  kpre1 = *(const bfx8*)&Kh[(size_t)(srow + 32) * HD_ + scol];
  vpre0 = *(const bfx8*)&Vh[(size_t)srow * VP_ + scol];
  vpre1 = *(const bfx8*)&Vh[(size_t)(srow + 32) * VP_ + scol];
  for (int kt = 0; kt < ntiles; kt++) {
    int kv0 = kt * 64;
    int dq = q0 - kv0;
    __syncthreads();
    *(bfx8*)&Ks[srow][scol] = kpre0;
    *(bfx8*)&Ks[srow + 32][scol] = kpre1;
    *(bfx8*)&Vs[srow][scol] = vpre0;
    *(bfx8*)&Vs[srow + 32][scol] = vpre1;
    __syncthreads();
    if (kt + 1 < ntiles) {
      int kn = kv0 + 64;
      kpre0 = *(const bfx8*)&Kh[(size_t)(kn + srow) * HD_ + scol];
      kpre1 = *(const bfx8*)&Kh[(size_t)(kn + srow + 32) * HD_ + scol];
      vpre0 = *(const bfx8*)&Vh[(size_t)srow * VP_ + kn + scol];
      vpre1 = *(const bfx8*)&Vh[(size_t)(srow + 32) * VP_ + kn + scol];
    }
    floatx4 sf[4];
#pragma unroll
    for (int nt = 0; nt < 4; nt++) {
      bfx8 kf0 = *(const bfx8*)&Ks[nt * 16 + l15][quad * 8];
      bfx8 kf1 = *(const bfx8*)&Ks[nt * 16 + l15][32 + quad * 8];
      floatx4 z = {0.f, 0.f, 0.f, 0.f};
      z = __builtin_amdgcn_mfma_f32_16x16x32_bf16(kf0, qf0, z, 0, 0, 0);
      sf[nt] = __builtin_amdgcn_mfma_f32_16x16x32_bf16(kf1, qf1, z, 0, 0, 0);
    }
#pragma unroll
    for (int nt = 0; nt < 4; nt++) {
      bfx4 pk;
#pragma unroll
      for (int r = 0; r < 4; r++) {
        int kvrel = nt * 16 + quad * 4 + r;
        float p = __expf(sf[nt][r] * 0.125f);
        p = (kvrel - l15 > dq) ? 0.f : p;
        ps += p;
        pk[r] = (__bf16)p;
      }
      *(bfx4*)&P[l15][nt * 16 + quad * 4] = pk;
    }
    bfx8 pa0 = *(const bfx8*)&P[l15][quad * 8];
    bfx8 pa1 = *(const bfx8*)&P[l15][32 + quad * 8];
#pragma unroll
    for (int ot = 0; ot < 4; ot++) {
      bfx8 vf0 = *(const bfx8*)&Vs[ot * 16 + l15][quad * 8];
      bfx8 vf1 = *(const bfx8*)&Vs[ot * 16 + l15][32 + quad * 8];
      oacc[ot] = __builtin_amdgcn_mfma_f32_16x16x32_bf16(pa0, vf0, oacc[ot], 0, 0, 0);
      oacc[ot] = __builtin_amdgcn_mfma_f32_16x16x32_bf16(pa1, vf1, oacc[ot], 0, 0, 0);
    }
  }
  ps += __shfl_xor(ps, 16);
  ps += __shfl_xor(ps, 32);
  float rl[4];
#pragma unroll
  for (int r = 0; r < 4; r++) rl[r] = 1.0f / __shfl(ps, quad * 4 + r);
#pragma unroll
  for (int ot = 0; ot < 4; ot++)
#pragma unroll
    for (int r = 0; r < 4; r++) {
      float val = oacc[ot][r] * rl[r];
      Ob[((size_t)b * S_ + q0 + quad * 4 + r) * AP_ + h * HD_ + ot * 16 + l15] = (__bf16)val;
    }
}

extern "C" void kernel_launch(void* const* d_in, const int* in_sizes, int n_in,
                              void* d_out, int out_size, void* d_ws, size_t ws_size,
                              hipStream_t stream) {
  const float* x   = (const float*)d_in[0];
  const float* cosT = (const float*)d_in[1];
  const float* sinT = (const float*)d_in[2];
  const float* wq  = (const float*)d_in[3];
  const float* wk  = (const float*)d_in[4];
  const float* wv  = (const float*)d_in[5];
  const float* wo  = (const float*)d_in[6];
  const float* qw  = (const float*)d_in[7];
  const float* kw  = (const float*)d_in[8];
  float* out = (float*)d_out;

  char* w = (char*)d_ws;
  __bf16* xbf   = (__bf16*)(w);                        // 4096*2056*2 = 16,842,752
  __bf16* wqkvT = (__bf16*)(w + 16842752);             // 1536*2056*2 =  6,316,032
  __bf16* woT   = (__bf16*)(w + 23158784);             // 2048*1032*2 =  4,227,072
  float*  qkv   = (float*) (w + 27385856);             // 4096*1536*4 = 25,165,824
  __bf16* attnO = (__bf16*)(w + 27385856);             // aliases qkv (qkv dead after norm_rope)
  __bf16* Qb    = (__bf16*)(w + 52551680);             //  8,388,608
  __bf16* Kb    = (__bf16*)(w + 60940288);             //  2,097,152
  __bf16* VTb   = (__bf16*)(w + 63037440);             // 2*4*64*2056*2 = 2,105,344 (end 65,142,784)

  cast_f32_bf16_pad<<<M_, 256, 0, stream>>>(x, xbf);
  dim3 tb(32, 8);
  transpose_cast<<<dim3(1024 / 32, 2048 / 32), tb, 0, stream>>>(wq, wqkvT, 2048, 1024, 0,    XP_);
  transpose_cast<<<dim3(256 / 32, 2048 / 32),  tb, 0, stream>>>(wk, wqkvT, 2048, 256,  1024, XP_);
  transpose_cast<<<dim3(256 / 32, 2048 / 32),  tb, 0, stream>>>(wv, wqkvT, 2048, 256,  1280, XP_);
  transpose_cast<<<dim3(2048 / 32, 1024 / 32), tb, 0, stream>>>(wo, woT,   1024, 2048, 0,    AP_);
  gemm_bf16_f32<<<dim3(NQKV_ / 128, M_ / 128), 256, 0, stream>>>(xbf, wqkvT, qkv, M_, NQKV_, H_, XP_, XP_, NQKV_);
  norm_rope_kernel<<<dim3(S_, B_), 256, 0, stream>>>(qkv, cosT, sinT, qw, kw, Qb, Kb, VTb);
  attn_kernel<<<dim3(32, NH_, B_), 256, 0, stream>>>(Qb, Kb, VTb, attnO);
  gemm_bf16_f32<<<dim3(H_ / 128, M_ / 128), 256, 0, stream>>>(attnO, woT, out, M_, H_, HQ_, AP_, AP_, H_);
}